// Round 9
// baseline (1115.603 us; speedup 1.0000x reference)
//
#include <hip/hip_runtime.h>
#include <hip/hip_cooperative_groups.h>
#include <hip/hip_bf16.h>
#include <float.h>

namespace cg = cooperative_groups;

#define DIM    128
#define NCLS   47
#define MAXD   64     // padded CSR slots/node; Poisson(12) max over 50k nodes ~35
#define BINCAP 8192   // records per bin region; lambda~3061, 93 sigma headroom

typedef __attribute__((ext_vector_type(8))) short bf16x8;
typedef __attribute__((ext_vector_type(4))) float f32x4;
typedef unsigned short u16;

// ---------- bf16 helpers ----------
__device__ inline unsigned short bf16_rne(float v) {
  unsigned u = __float_as_uint(v);
  return (unsigned short)((u + 0x7FFFu + ((u >> 16) & 1u)) >> 16);
}

__device__ inline void split_bf16(float v, unsigned short& hi, unsigned short& lo) {
  unsigned int u = __float_as_uint(v);
  unsigned int r = (u + 0x7FFFu + ((u >> 16) & 1u)) >> 16;
  hi = (unsigned short)r;
  float hf = __uint_as_float(r << 16);
  float l = v - hf;
  unsigned int ul = __float_as_uint(l);
  unsigned int rl = (ul + 0x7FFFu + ((ul >> 16) & 1u)) >> 16;
  lo = (unsigned short)rl;
}

__device__ inline uint4 pack8(const unsigned short* h) {
  uint4 u;
  u.x = (unsigned)h[0] | ((unsigned)h[1] << 16);
  u.y = (unsigned)h[2] | ((unsigned)h[3] << 16);
  u.z = (unsigned)h[4] | ((unsigned)h[5] << 16);
  u.w = (unsigned)h[6] | ((unsigned)h[7] << 16);
  return u;
}

// ---------- init0: zero the padded bin counters (must precede S1 atomics) ----------
__global__ __launch_bounds__(256) void k_init0(int* __restrict__ binCnt) {
  int i = blockIdx.x * 256 + threadIdx.x;
  if (i < 4096) binCnt[i] = 0;
}

// ---------- prep: S1 binning + packB + packC + cvt + eidx sentinel + row-N zero ----
// S1 blocks first (latency-bound LDS-histogram binning, 196 global atomics/block);
// BW-bound pack/cvt/sentinel work runs under their shadow.
__global__ __launch_bounds__(256) void k_prep(const float* __restrict__ w_self,
                                              const float* __restrict__ w_neigh,
                                              const float* __restrict__ wc,
                                              const float* __restrict__ feat,
                                              const int* __restrict__ src,
                                              const int* __restrict__ dst,
                                              uint4* __restrict__ Bhi,
                                              uint4* __restrict__ Blo,
                                              uint4* __restrict__ Chi,
                                              uint4* __restrict__ Clo,
                                              unsigned short* __restrict__ P0,
                                              unsigned short* __restrict__ P1,
                                              unsigned short* __restrict__ P2,
                                              int* __restrict__ binCnt,
                                              unsigned* __restrict__ binbuf,
                                              u16* __restrict__ eidx,
                                              int n, long total8, long t8,
                                              int E, int nS1, int nCvt) {
  int bid = blockIdx.x, tid = threadIdx.x;
  if (bid < nS1) {                     // S1: 4096 edges/block, 16/thread strided
    __shared__ int h[256], r[256], base[256];
    h[tid] = 0; r[tid] = 0;
    __syncthreads();
    unsigned rec[16];
    int e0 = bid * 4096 + tid;
#pragma unroll
    for (int j = 0; j < 16; ++j) {
      int e = e0 + j * 256;            // coalesced
      unsigned v = 0xFFFFFFFFu;
      if (e < E) {
        int d = dst[e], s = src[e];
        v = ((unsigned)d << 16) | (unsigned)s;
        atomicAdd(&h[d >> 8], 1);
      }
      rec[j] = v;
    }
    __syncthreads();
    {
      int c = h[tid];
      base[tid] = (c > 0) ? atomicAdd(&binCnt[tid * 16], c) : 0;
    }
    __syncthreads();
#pragma unroll
    for (int j = 0; j < 16; ++j) {
      unsigned v = rec[j];
      if (v != 0xFFFFFFFFu) {
        int b = v >> 24;               // dst >> 8
        int rk = atomicAdd(&r[b], 1);  // LDS rank
        int pos = base[b] + rk;
        if (pos < BINCAP) binbuf[(size_t)b * BINCAP + pos] = v;
      }
    }
    return;
  }
  bid -= nS1;
  if (bid < 48) {                      // packB: 192 units (4/block)
    int unit = bid * 4 + (tid >> 6);
    int lane = tid & 63;
    int lt = unit >> 6, rem = unit & 63, kt = rem >> 3, ct = rem & 7;
    int col = ct * 16 + (lane & 15);
    unsigned short h8[8], lw[8];
#pragma unroll
    for (int j = 0; j < 8; ++j) {
      int kg = kt * 32 + (lane >> 4) * 8 + j;
      float v = (kg < 128) ? w_self[(size_t)lt * DIM * DIM + (size_t)kg * DIM + col]
                           : w_neigh[(size_t)lt * DIM * DIM + (size_t)(kg - 128) * DIM + col];
      split_bf16(v, h8[j], lw[j]);
    }
    size_t idx = (((size_t)lt * 64 + kt * 8 + ct) * 64 + lane);
    Bhi[idx] = pack8(h8);
    Blo[idx] = pack8(lw);
  } else if (bid < 51) {               // packC: 12 units
    int unit = (bid - 48) * 4 + (tid >> 6);
    if (unit < 12) {
      int lane = tid & 63;
      int kt = unit / 3, ct = unit % 3;
      int col = ct * 16 + (lane & 15);
      unsigned short h8[8], lw[8];
#pragma unroll
      for (int j = 0; j < 8; ++j) {
        int k = kt * 32 + (lane >> 4) * 8 + j;
        float v = (col < NCLS) ? wc[(size_t)k * NCLS + col] : 0.f;
        split_bf16(v, h8[j], lw[j]);
      }
      size_t idx = (size_t)(kt * 3 + ct) * 64 + lane;
      Chi[idx] = pack8(h8);
      Clo[idx] = pack8(lw);
    }
  } else if (bid < 51 + nCvt) {        // cvt features -> bf16 plane P0
    long i = (long)(bid - 51) * 256 + tid;
    if (i < total8) {
      const float* s = feat + i * 8;
      unsigned short h8[8];
#pragma unroll
      for (int j = 0; j < 8; ++j) h8[j] = bf16_rne(s[j]);
      *(uint4*)&P0[i * 8] = pack8(h8);
    }
  } else {                             // eidx sentinel fill + row-N zero
    long j = (long)(bid - 51 - nCvt);
    long i = j * 256 + tid;
    if (i < t8) {                      // t8 == N*MAXD/8 (ushort8 = 16B stores)
      unsigned s2 = (unsigned)n | ((unsigned)n << 16);
      uint4 v = {s2, s2, s2, s2};
      ((uint4*)eidx)[i] = v;
    }
    if (j == 0 && tid < 16) {          // zero row N of every gather source
      uint4 z = {0u, 0u, 0u, 0u};
      ((uint4*)(P0 + (size_t)n * DIM))[tid] = z;
      ((uint4*)(P1 + (size_t)n * DIM))[tid] = z;
      ((uint4*)(P2 + (size_t)n * DIM))[tid] = z;
    }
  }
}

// ---------- cooperative: csr -> 3 x (agg -> mm), grid.sync between phases ----------
// Replaces 7 dispatches (csr + 3 agg + 3 mm) with one launch: kills ~6 launch
// gaps. Bodies are verbatim round-7 kernels, grid-strided; grid sized by
// occupancy query so co-residency (and grid.sync validity) is guaranteed.
__global__ __launch_bounds__(256, 4) void k_coop(unsigned short* P0,
                                                 unsigned short* P1,
                                                 unsigned short* P2,
                                                 unsigned short* HN,
                                                 int* cnt, u16* eidx,
                                                 const unsigned* binbuf,
                                                 const int* binCnt,
                                                 const uint4* BhiB,
                                                 const uint4* BloB,
                                                 const float* wb,
                                                 const uint4* Chi,
                                                 const uint4* Clo,
                                                 const float* bc,
                                                 float* out,
                                                 int n, int nUnits, int nTiles,
                                                 int nBins) {
  cg::grid_group grid = cg::this_grid();
  __shared__ char U[34816];            // csr c256 | mm B-dbuf (32KB) + T overlay
  uint4* Bs = (uint4*)U;
  int tid = threadIdx.x, lane = tid & 63, w = tid >> 6;

  // ---- phase 0: per-bin CSR build (LDS ranks, zero global atomics) ----
  for (int b = blockIdx.x; b < nBins; b += gridDim.x) {
    int* c256 = (int*)U;
    c256[tid] = 0;
    __syncthreads();
    int count = binCnt[b * 16];
    if (count > BINCAP) count = BINCAP;
    const unsigned* rec = binbuf + (size_t)b * BINCAP;
    for (int i = tid; i < count; i += 256) {
      unsigned v = rec[i];
      int d = v >> 16;
      int rk = atomicAdd(&c256[d & 255], 1);
      if (rk < MAXD) eidx[(size_t)d * MAXD + rk] = (u16)(v & 0xFFFFu);
    }
    __syncthreads();
    int node = (b << 8) | tid;
    if (node < n) cnt[node] = c256[tid];
    __syncthreads();                   // before c256 reuse
  }
  __threadfence();
  grid.sync();

  for (int l = 0; l < 3; ++l) {
    const unsigned short* hin = (l == 0) ? P0 : ((l == 1) ? P1 : P2);
    unsigned short* hout = (l == 0) ? P1 : P2;
    int last = (l == 2);

    // ---- agg phase: wave/node, branch-free 16-edge chunks (verbatim agg9) ----
    for (int u = blockIdx.x; u < nUnits; u += gridDim.x) {
      int node = u * 4 + (tid >> 6);
      if (node < n) {
        int g = lane >> 4, li = lane & 15;
        int d = cnt[node];
        int dcl = d < MAXD ? d : MAXD;
        int s = node * MAXD;
        int nch = (dcl + 15) >> 4;
        float acc[8];
#pragma unroll
        for (int k = 0; k < 8; ++k) acc[k] = 0.f;
        for (int c = 0; c < nch; ++c) {
          int base = s + c * 16 + g;
          int u0 = eidx[base];
          int u1 = eidx[base + 4];
          int u2 = eidx[base + 8];
          int u3 = eidx[base + 12];
          uint4 v0 = *(const uint4*)(hin + (size_t)u0 * DIM + li * 8);
          uint4 v1 = *(const uint4*)(hin + (size_t)u1 * DIM + li * 8);
          uint4 v2 = *(const uint4*)(hin + (size_t)u2 * DIM + li * 8);
          uint4 v3 = *(const uint4*)(hin + (size_t)u3 * DIM + li * 8);
          acc[0] += __uint_as_float(v0.x << 16); acc[1] += __uint_as_float(v0.x & 0xffff0000u);
          acc[2] += __uint_as_float(v0.y << 16); acc[3] += __uint_as_float(v0.y & 0xffff0000u);
          acc[4] += __uint_as_float(v0.z << 16); acc[5] += __uint_as_float(v0.z & 0xffff0000u);
          acc[6] += __uint_as_float(v0.w << 16); acc[7] += __uint_as_float(v0.w & 0xffff0000u);
          acc[0] += __uint_as_float(v1.x << 16); acc[1] += __uint_as_float(v1.x & 0xffff0000u);
          acc[2] += __uint_as_float(v1.y << 16); acc[3] += __uint_as_float(v1.y & 0xffff0000u);
          acc[4] += __uint_as_float(v1.z << 16); acc[5] += __uint_as_float(v1.z & 0xffff0000u);
          acc[6] += __uint_as_float(v1.w << 16); acc[7] += __uint_as_float(v1.w & 0xffff0000u);
          acc[0] += __uint_as_float(v2.x << 16); acc[1] += __uint_as_float(v2.x & 0xffff0000u);
          acc[2] += __uint_as_float(v2.y << 16); acc[3] += __uint_as_float(v2.y & 0xffff0000u);
          acc[4] += __uint_as_float(v2.z << 16); acc[5] += __uint_as_float(v2.z & 0xffff0000u);
          acc[6] += __uint_as_float(v2.w << 16); acc[7] += __uint_as_float(v2.w & 0xffff0000u);
          acc[0] += __uint_as_float(v3.x << 16); acc[1] += __uint_as_float(v3.x & 0xffff0000u);
          acc[2] += __uint_as_float(v3.y << 16); acc[3] += __uint_as_float(v3.y & 0xffff0000u);
          acc[4] += __uint_as_float(v3.z << 16); acc[5] += __uint_as_float(v3.z & 0xffff0000u);
          acc[6] += __uint_as_float(v3.w << 16); acc[7] += __uint_as_float(v3.w & 0xffff0000u);
        }
#pragma unroll
        for (int k = 0; k < 8; ++k) {
          acc[k] += __shfl_xor(acc[k], 16);
          acc[k] += __shfl_xor(acc[k], 32);
        }
        if (g == 0) {
          float idg = 1.0f / (float)(d > 1 ? d : 1);
          unsigned short hb[8];
#pragma unroll
          for (int k = 0; k < 8; ++k) hb[k] = bf16_rne(acc[k] * idg);
          *(uint4*)(HN + (size_t)node * DIM + li * 8) = pack8(hb);
        }
      }
    }
    __threadfence();
    grid.sync();

    // ---- mm phase: 4 waves x 32 rows, B staged through LDS (verbatim mm2) ----
    const uint4* Bhi = BhiB + (size_t)l * 4096;
    const uint4* Blo = BloB + (size_t)l * 4096;
    const float* bias = wb + (size_t)l * DIM;
    for (int t = blockIdx.x; t < nTiles; t += gridDim.x) {
      __syncthreads();                 // protect U from previous tile's T reads
      int rb = t * 128 + w * 32;
      f32x4 macc[2][8];
#pragma unroll
      for (int rf = 0; rf < 2; ++rf)
#pragma unroll
        for (int ct = 0; ct < 8; ++ct) macc[rf][ct] = (f32x4){0.f, 0.f, 0.f, 0.f};

      int r0 = rb + (lane & 15);      if (r0 > n - 1) r0 = n - 1;
      int r1 = rb + 16 + (lane & 15); if (r1 > n - 1) r1 = n - 1;
      int koff = (lane >> 4) * 8;
      const unsigned short* a0s = hin + (size_t)r0 * DIM + koff;
      const unsigned short* a1s = hin + (size_t)r1 * DIM + koff;
      const unsigned short* a0n = HN + (size_t)r0 * DIM + koff;
      const unsigned short* a1n = HN + (size_t)r1 * DIM + koff;

#define STAGE_B(kt_, buf_)                                                    \
  {                                                                           \
    const uint4* hsrc = Bhi + (size_t)(kt_) * 512;                            \
    const uint4* lsrc = Blo + (size_t)(kt_) * 512;                            \
    uint4* dstb = Bs + (size_t)(buf_) * 1024;                                 \
    dstb[tid]        = hsrc[tid];                                             \
    dstb[tid + 256]  = hsrc[tid + 256];                                       \
    dstb[tid + 512]  = lsrc[tid];                                             \
    dstb[tid + 768]  = lsrc[tid + 256];                                       \
  }

      STAGE_B(0, 0);
      __syncthreads();

#pragma unroll
      for (int kt = 0; kt < 8; ++kt) {
        if (kt < 7) STAGE_B(kt + 1, (kt + 1) & 1);
        int buf = kt & 1;
        bf16x8 a0 = (kt < 4) ? *(const bf16x8*)(a0s + kt * 32)
                             : *(const bf16x8*)(a0n + (kt - 4) * 32);
        bf16x8 a1 = (kt < 4) ? *(const bf16x8*)(a1s + kt * 32)
                             : *(const bf16x8*)(a1n + (kt - 4) * 32);
        const uint4* bb = Bs + (size_t)buf * 1024;
#pragma unroll
        for (int ct = 0; ct < 8; ++ct) {
          bf16x8 bh = *(const bf16x8*)&bb[ct * 64 + lane];
          bf16x8 bl = *(const bf16x8*)&bb[512 + ct * 64 + lane];
          macc[0][ct] = __builtin_amdgcn_mfma_f32_16x16x32_bf16(a0, bh, macc[0][ct], 0, 0, 0);
          macc[0][ct] = __builtin_amdgcn_mfma_f32_16x16x32_bf16(a0, bl, macc[0][ct], 0, 0, 0);
          macc[1][ct] = __builtin_amdgcn_mfma_f32_16x16x32_bf16(a1, bh, macc[1][ct], 0, 0, 0);
          macc[1][ct] = __builtin_amdgcn_mfma_f32_16x16x32_bf16(a1, bl, macc[1][ct], 0, 0, 0);
        }
        __syncthreads();
      }
#undef STAGE_B

      // ---- epilogue: U reused as T (wave-local region) ----
      char* tw = U + (size_t)w * 32 * 272;
#pragma unroll
      for (int rf = 0; rf < 2; ++rf)
#pragma unroll
        for (int ct = 0; ct < 8; ++ct) {
          float bv = bias[ct * 16 + (lane & 15)];
#pragma unroll
          for (int q = 0; q < 4; ++q) {
            float val = fmaxf(macc[rf][ct][q] + bv, 0.f);
            int row = rf * 16 + (lane >> 4) * 4 + q;
            int key = ((row >> 2) & 3) << 5;
            int cb = (ct * 32 + (lane & 15) * 2) ^ key;
            *(unsigned short*)(tw + row * 272 + cb) = bf16_rne(val);
          }
        }

      if (!last) {
#pragma unroll
        for (int rr = 0; rr < 2; ++rr) {
          int r = rr * 16 + (lane >> 2);
          int grow = rb + r;
          if (grow < n) {
            int key = ((r >> 2) & 3) << 5;
            int cb0 = (lane & 3) * 64;
#pragma unroll
            for (int j = 0; j < 4; ++j) {
              uint4 v = *(const uint4*)(tw + r * 272 + ((cb0 + j * 16) ^ key));
              *(uint4*)(hout + (size_t)grow * DIM + (cb0 + j * 16) / 2) = v;
            }
          }
        }
      } else {
#pragma unroll
        for (int rf = 0; rf < 2; ++rf) {
          f32x4 cacc[3];
#pragma unroll
          for (int ct = 0; ct < 3; ++ct) cacc[ct] = (f32x4){0.f, 0.f, 0.f, 0.f};
          int row = rf * 16 + (lane & 15);
          int key = ((row >> 2) & 3) << 5;
#pragma unroll
          for (int kt = 0; kt < 4; ++kt) {
            int bo = (kt * 64 + (lane >> 4) * 16) ^ key;
            bf16x8 a = *(const bf16x8*)(tw + row * 272 + bo);
#pragma unroll
            for (int ct = 0; ct < 3; ++ct) {
              bf16x8 bh = *(const bf16x8*)&Chi[(size_t)(kt * 3 + ct) * 64 + lane];
              bf16x8 bl = *(const bf16x8*)&Clo[(size_t)(kt * 3 + ct) * 64 + lane];
              cacc[ct] = __builtin_amdgcn_mfma_f32_16x16x32_bf16(a, bh, cacc[ct], 0, 0, 0);
              cacc[ct] = __builtin_amdgcn_mfma_f32_16x16x32_bf16(a, bl, cacc[ct], 0, 0, 0);
            }
          }
          int c0 = (lane & 15);
          int c1 = 16 + (lane & 15);
          int c2 = 32 + (lane & 15);
          bool v2 = c2 < NCLS;
          float b0 = bc[c0], b1 = bc[c1], b2 = v2 ? bc[c2] : 0.f;
#pragma unroll
          for (int q = 0; q < 4; ++q) {
            int grow = rb + rf * 16 + (lane >> 4) * 4 + q;
            float l0 = cacc[0][q] + b0;
            float l1 = cacc[1][q] + b1;
            float l2 = v2 ? cacc[2][q] + b2 : -FLT_MAX;
            float m = fmaxf(l0, fmaxf(l1, l2));
#pragma unroll
            for (int off = 8; off >= 1; off >>= 1) m = fmaxf(m, __shfl_xor(m, off));
            float e0 = __expf(l0 - m);
            float e1 = __expf(l1 - m);
            float e2 = v2 ? __expf(l2 - m) : 0.f;
            float sden = e0 + e1 + e2;
#pragma unroll
            for (int off = 8; off >= 1; off >>= 1) sden += __shfl_xor(sden, off);
            float inv = 1.0f / sden;
            if (grow < n) {
              out[(size_t)grow * NCLS + c0] = e0 * inv;
              out[(size_t)grow * NCLS + c1] = e1 * inv;
              if (v2) out[(size_t)grow * NCLS + c2] = e2 * inv;
            }
          }
        }
      }
    }
    __threadfence();
    grid.sync();
  }
}

extern "C" void kernel_launch(void* const* d_in, const int* in_sizes, int n_in,
                              void* d_out, int out_size, void* d_ws, size_t ws_size,
                              hipStream_t stream) {
  const float* feat   = (const float*)d_in[0];
  const int*   src    = (const int*)d_in[1];
  const int*   dst    = (const int*)d_in[2];
  const float* w_self = (const float*)d_in[3];
  const float* w_neigh= (const float*)d_in[4];
  const float* wb     = (const float*)d_in[5];
  const float* wc     = (const float*)d_in[6];
  const float* bc     = (const float*)d_in[7];
  float* out = (float*)d_out;

  const int N = in_sizes[0] / DIM;
  const int E = in_sizes[1];
  const size_t PS  = (size_t)N * DIM;        // plane elems (data rows)
  const size_t PSP = (size_t)(N + 1) * DIM;  // +1 sentinel row

  // workspace layout (~68 MB)
  unsigned short* P0 = (unsigned short*)d_ws;   // features bf16 (+row N = 0)
  unsigned short* P1 = P0 + PSP;                // layer0 out / layer2 out
  unsigned short* P2 = P1 + PSP;                // layer1 out
  unsigned short* HN = P2 + PSP;                // neighbor means (N rows)
  int*   cnt  = (int*)(HN + PS);
  u16*   eidx = (u16*)(cnt + N);                // N*MAXD padded u16 slots
  uintptr_t aln = ((uintptr_t)(eidx + (size_t)N * MAXD) + 255) & ~(uintptr_t)255;
  uint4* Bhi = (uint4*)aln;                     // 3 * 4096
  uint4* Blo = Bhi + 3 * 4096;
  uint4* Chi = Blo + 3 * 4096;                  // 12*64
  uint4* Clo = Chi + 12 * 64;
  int* binCnt = (int*)(Clo + 12 * 64);          // 256 counters, padded x16
  unsigned* binbuf = (unsigned*)(binCnt + 4096);// 256 * BINCAP records

  // 1) zero bin counters (tiny; must precede S1 atomics)
  k_init0<<<16, 256, 0, stream>>>(binCnt);

  // 2) prep: S1 binning + packs + cvt + eidx sentinel + row-N zero
  long total8 = (long)(PS / 8);
  long t8 = (long)N * MAXD / 8;                 // ushort8 stores
  int nCvt = (int)((total8 + 255) / 256);
  int nSent = (int)((t8 + 255) / 256);
  int nS1 = (E + 4095) / 4096;
  k_prep<<<nS1 + 51 + nCvt + nSent, 256, 0, stream>>>(
      w_self, w_neigh, wc, feat, src, dst,
      Bhi, Blo, Chi, Clo, P0, P1, P2,
      binCnt, binbuf, eidx, N, total8, t8, E, nS1, nCvt);

  // 3) cooperative: csr -> 3 x (agg -> mm); grid sized for guaranteed co-residency
  int dev = 0;
  (void)hipGetDevice(&dev);
  int numCU = 0;
  (void)hipDeviceGetAttribute(&numCU, hipDeviceAttributeMultiprocessorCount, dev);
  if (numCU <= 0) numCU = 256;
  int perCU = 0;
  if (hipOccupancyMaxActiveBlocksPerMultiprocessor(&perCU, k_coop, 256, 0) != hipSuccess
      || perCU < 1)
    perCU = 4;                                  // __launch_bounds__(256,4) design point
  int nUnits = (N + 3) / 4, nTiles = (N + 127) / 128, nBins = (N + 255) >> 8;
  int gridC = numCU * perCU;
  if (gridC > nUnits) gridC = nUnits;

  unsigned short* P0a = P0; unsigned short* P1a = P1; unsigned short* P2a = P2;
  unsigned short* HNa = HN;
  int* cnta = cnt; u16* eidxa = eidx;
  const unsigned* binbufa = binbuf; const int* binCnta = binCnt;
  const uint4* Bhia = Bhi; const uint4* Bloa = Blo;
  const float* wba = wb;
  const uint4* Chia = Chi; const uint4* Cloa = Clo;
  const float* bca = bc; float* outa = out;
  int Na = N;
  void* kargs[] = {
    (void*)&P0a, (void*)&P1a, (void*)&P2a, (void*)&HNa,
    (void*)&cnta, (void*)&eidxa, (void*)&binbufa, (void*)&binCnta,
    (void*)&Bhia, (void*)&Bloa, (void*)&wba,
    (void*)&Chia, (void*)&Cloa, (void*)&bca, (void*)&outa,
    (void*)&Na, (void*)&nUnits, (void*)&nTiles, (void*)&nBins };
  (void)hipLaunchCooperativeKernel(k_coop, dim3(gridC), dim3(256), kargs, 0, stream);
}

// Round 10
// 164.657 us; speedup vs baseline: 6.7753x; 6.7753x over previous
//
#include <hip/hip_runtime.h>
#include <hip/hip_bf16.h>
#include <float.h>

#define DIM    128
#define NCLS   47
#define MAXD   64     // padded CSR slots/node; Poisson(12) max over 50k nodes ~35
#define BINCAP 8192   // records per bin region; lambda~3061, 93 sigma headroom

typedef __attribute__((ext_vector_type(8))) short bf16x8;
typedef __attribute__((ext_vector_type(4))) float f32x4;
typedef unsigned short u16;

// ---------- bf16 helpers ----------
__device__ inline unsigned short bf16_rne(float v) {
  unsigned u = __float_as_uint(v);
  return (unsigned short)((u + 0x7FFFu + ((u >> 16) & 1u)) >> 16);
}

__device__ inline void split_bf16(float v, unsigned short& hi, unsigned short& lo) {
  unsigned int u = __float_as_uint(v);
  unsigned int r = (u + 0x7FFFu + ((u >> 16) & 1u)) >> 16;
  hi = (unsigned short)r;
  float hf = __uint_as_float(r << 16);
  float l = v - hf;
  unsigned int ul = __float_as_uint(l);
  unsigned int rl = (ul + 0x7FFFu + ((ul >> 16) & 1u)) >> 16;
  lo = (unsigned short)rl;
}

__device__ inline uint4 pack8(const unsigned short* h) {
  uint4 u;
  u.x = (unsigned)h[0] | ((unsigned)h[1] << 16);
  u.y = (unsigned)h[2] | ((unsigned)h[3] << 16);
  u.z = (unsigned)h[4] | ((unsigned)h[5] << 16);
  u.w = (unsigned)h[6] | ((unsigned)h[7] << 16);
  return u;
}

// ---------- init0: zero the padded bin counters (must precede S1 atomics) ----------
__global__ __launch_bounds__(256) void k_init0(int* __restrict__ binCnt) {
  int i = blockIdx.x * 256 + threadIdx.x;
  if (i < 4096) binCnt[i] = 0;
}

// ---------- prep: S1 binning + packB + packC + cvt + eidx sentinel + row-N zero ----
// S1 blocks first (latency-bound LDS-histogram binning, 196 global atomics/block);
// BW-bound pack/cvt/sentinel work runs under their shadow.
__global__ __launch_bounds__(256) void k_prep(const float* __restrict__ w_self,
                                              const float* __restrict__ w_neigh,
                                              const float* __restrict__ wc,
                                              const float* __restrict__ feat,
                                              const int* __restrict__ src,
                                              const int* __restrict__ dst,
                                              uint4* __restrict__ Bhi,
                                              uint4* __restrict__ Blo,
                                              uint4* __restrict__ Chi,
                                              uint4* __restrict__ Clo,
                                              unsigned short* __restrict__ P0,
                                              unsigned short* __restrict__ P1,
                                              unsigned short* __restrict__ P2,
                                              int* __restrict__ binCnt,
                                              unsigned* __restrict__ binbuf,
                                              u16* __restrict__ eidx,
                                              int n, long total8, long t8,
                                              int E, int nS1, int nCvt) {
  int bid = blockIdx.x, tid = threadIdx.x;
  if (bid < nS1) {                     // S1: 4096 edges/block, 16/thread strided
    __shared__ int h[256], r[256], base[256];
    h[tid] = 0; r[tid] = 0;
    __syncthreads();
    unsigned rec[16];
    int e0 = bid * 4096 + tid;
#pragma unroll
    for (int j = 0; j < 16; ++j) {
      int e = e0 + j * 256;            // coalesced
      unsigned v = 0xFFFFFFFFu;
      if (e < E) {
        int d = dst[e], s = src[e];
        v = ((unsigned)d << 16) | (unsigned)s;
        atomicAdd(&h[d >> 8], 1);
      }
      rec[j] = v;
    }
    __syncthreads();
    {
      int c = h[tid];
      base[tid] = (c > 0) ? atomicAdd(&binCnt[tid * 16], c) : 0;
    }
    __syncthreads();
#pragma unroll
    for (int j = 0; j < 16; ++j) {
      unsigned v = rec[j];
      if (v != 0xFFFFFFFFu) {
        int b = v >> 24;               // dst >> 8
        int rk = atomicAdd(&r[b], 1);  // LDS rank
        int pos = base[b] + rk;
        if (pos < BINCAP) binbuf[(size_t)b * BINCAP + pos] = v;
      }
    }
    return;
  }
  bid -= nS1;
  if (bid < 48) {                      // packB: 192 units (4/block)
    int unit = bid * 4 + (tid >> 6);
    int lane = tid & 63;
    int lt = unit >> 6, rem = unit & 63, kt = rem >> 3, ct = rem & 7;
    int col = ct * 16 + (lane & 15);
    unsigned short h8[8], lw[8];
#pragma unroll
    for (int j = 0; j < 8; ++j) {
      int kg = kt * 32 + (lane >> 4) * 8 + j;
      float v = (kg < 128) ? w_self[(size_t)lt * DIM * DIM + (size_t)kg * DIM + col]
                           : w_neigh[(size_t)lt * DIM * DIM + (size_t)(kg - 128) * DIM + col];
      split_bf16(v, h8[j], lw[j]);
    }
    size_t idx = (((size_t)lt * 64 + kt * 8 + ct) * 64 + lane);
    Bhi[idx] = pack8(h8);
    Blo[idx] = pack8(lw);
  } else if (bid < 51) {               // packC: 12 units
    int unit = (bid - 48) * 4 + (tid >> 6);
    if (unit < 12) {
      int lane = tid & 63;
      int kt = unit / 3, ct = unit % 3;
      int col = ct * 16 + (lane & 15);
      unsigned short h8[8], lw[8];
#pragma unroll
      for (int j = 0; j < 8; ++j) {
        int k = kt * 32 + (lane >> 4) * 8 + j;
        float v = (col < NCLS) ? wc[(size_t)k * NCLS + col] : 0.f;
        split_bf16(v, h8[j], lw[j]);
      }
      size_t idx = (size_t)(kt * 3 + ct) * 64 + lane;
      Chi[idx] = pack8(h8);
      Clo[idx] = pack8(lw);
    }
  } else if (bid < 51 + nCvt) {        // cvt features -> bf16 plane P0
    long i = (long)(bid - 51) * 256 + tid;
    if (i < total8) {
      const float* s = feat + i * 8;
      unsigned short h8[8];
#pragma unroll
      for (int j = 0; j < 8; ++j) h8[j] = bf16_rne(s[j]);
      *(uint4*)&P0[i * 8] = pack8(h8);
    }
  } else {                             // eidx sentinel fill + row-N zero
    long j = (long)(bid - 51 - nCvt);
    long i = j * 256 + tid;
    if (i < t8) {                      // t8 == N*MAXD/8 (ushort8 = 16B stores)
      unsigned s2 = (unsigned)n | ((unsigned)n << 16);
      uint4 v = {s2, s2, s2, s2};
      ((uint4*)eidx)[i] = v;
    }
    if (j == 0 && tid < 16) {          // zero row N of every gather source
      uint4 z = {0u, 0u, 0u, 0u};
      ((uint4*)(P0 + (size_t)n * DIM))[tid] = z;
      ((uint4*)(P1 + (size_t)n * DIM))[tid] = z;
      ((uint4*)(P2 + (size_t)n * DIM))[tid] = z;
    }
  }
}

// ---------- S2: per-bin CSR build (LDS ranks, zero global atomics) ----------
__global__ __launch_bounds__(256) void k_csr(const unsigned* __restrict__ binbuf,
                                             const int* __restrict__ binCnt,
                                             int* __restrict__ cnt,
                                             u16* __restrict__ eidx, int n) {
  __shared__ int c256[256];
  int b = blockIdx.x, tid = threadIdx.x;
  c256[tid] = 0;
  __syncthreads();
  int count = binCnt[b * 16];
  if (count > BINCAP) count = BINCAP;
  const unsigned* rec = binbuf + (size_t)b * BINCAP;
  for (int i = tid; i < count; i += 256) {
    unsigned v = rec[i];
    int d = v >> 16;
    int rk = atomicAdd(&c256[d & 255], 1);
    if (rk < MAXD) eidx[(size_t)d * MAXD + rk] = (u16)(v & 0xFFFFu);
  }
  __syncthreads();
  int node = (b << 8) | tid;
  if (node < n) cnt[node] = c256[tid];
}

// ---------- mean aggregation: wave/node, branch-free 16-edge chunks ----------
__global__ __launch_bounds__(256) void k_agg9(const unsigned short* __restrict__ plane,
                                              unsigned short* __restrict__ hn,
                                              const int* __restrict__ cnt,
                                              const u16* __restrict__ eidx, int n) {
  int node = blockIdx.x * 4 + (threadIdx.x >> 6);
  if (node >= n) return;
  int lane = threadIdx.x & 63;
  int g = lane >> 4, li = lane & 15;
  int d = cnt[node];
  int dcl = d < MAXD ? d : MAXD;
  int s = node * MAXD;
  int nch = (dcl + 15) >> 4;
  float acc[8];
#pragma unroll
  for (int k = 0; k < 8; ++k) acc[k] = 0.f;

  for (int c = 0; c < nch; ++c) {
    int base = s + c * 16 + g;
    int u0 = eidx[base];
    int u1 = eidx[base + 4];
    int u2 = eidx[base + 8];
    int u3 = eidx[base + 12];
    uint4 v0 = *(const uint4*)(plane + (size_t)u0 * DIM + li * 8);
    uint4 v1 = *(const uint4*)(plane + (size_t)u1 * DIM + li * 8);
    uint4 v2 = *(const uint4*)(plane + (size_t)u2 * DIM + li * 8);
    uint4 v3 = *(const uint4*)(plane + (size_t)u3 * DIM + li * 8);
    acc[0] += __uint_as_float(v0.x << 16); acc[1] += __uint_as_float(v0.x & 0xffff0000u);
    acc[2] += __uint_as_float(v0.y << 16); acc[3] += __uint_as_float(v0.y & 0xffff0000u);
    acc[4] += __uint_as_float(v0.z << 16); acc[5] += __uint_as_float(v0.z & 0xffff0000u);
    acc[6] += __uint_as_float(v0.w << 16); acc[7] += __uint_as_float(v0.w & 0xffff0000u);
    acc[0] += __uint_as_float(v1.x << 16); acc[1] += __uint_as_float(v1.x & 0xffff0000u);
    acc[2] += __uint_as_float(v1.y << 16); acc[3] += __uint_as_float(v1.y & 0xffff0000u);
    acc[4] += __uint_as_float(v1.z << 16); acc[5] += __uint_as_float(v1.z & 0xffff0000u);
    acc[6] += __uint_as_float(v1.w << 16); acc[7] += __uint_as_float(v1.w & 0xffff0000u);
    acc[0] += __uint_as_float(v2.x << 16); acc[1] += __uint_as_float(v2.x & 0xffff0000u);
    acc[2] += __uint_as_float(v2.y << 16); acc[3] += __uint_as_float(v2.y & 0xffff0000u);
    acc[4] += __uint_as_float(v2.z << 16); acc[5] += __uint_as_float(v2.z & 0xffff0000u);
    acc[6] += __uint_as_float(v2.w << 16); acc[7] += __uint_as_float(v2.w & 0xffff0000u);
    acc[0] += __uint_as_float(v3.x << 16); acc[1] += __uint_as_float(v3.x & 0xffff0000u);
    acc[2] += __uint_as_float(v3.y << 16); acc[3] += __uint_as_float(v3.y & 0xffff0000u);
    acc[4] += __uint_as_float(v3.z << 16); acc[5] += __uint_as_float(v3.z & 0xffff0000u);
    acc[6] += __uint_as_float(v3.w << 16); acc[7] += __uint_as_float(v3.w & 0xffff0000u);
  }
#pragma unroll
  for (int k = 0; k < 8; ++k) {
    acc[k] += __shfl_xor(acc[k], 16);
    acc[k] += __shfl_xor(acc[k], 32);
  }
  if (g == 0) {
    float idg = 1.0f / (float)(d > 1 ? d : 1);
    unsigned short hb[8];
#pragma unroll
    for (int k = 0; k < 8; ++k) hb[k] = bf16_rne(acc[k] * idg);
    *(uint4*)(hn + (size_t)node * DIM + li * 8) = pack8(hb);
  }
}

// ---------- layer GEMM: 4 waves x 32 rows, B staged through LDS (dbuf) ----------
template <int LAST>
__global__ __launch_bounds__(256) void k_mm2(const unsigned short* __restrict__ plane,
                                             const unsigned short* __restrict__ hn,
                                             const uint4* __restrict__ Bhi,
                                             const uint4* __restrict__ Blo,
                                             const float* __restrict__ bias,
                                             unsigned short* __restrict__ oplane,
                                             const uint4* __restrict__ Chi,
                                             const uint4* __restrict__ Clo,
                                             const float* __restrict__ bc,
                                             float* __restrict__ out,
                                             int n) {
  __shared__ char U[34816];          // max(2x16KB B dbuf = 32768, T = 128*272 = 34816)
  uint4* Bs = (uint4*)U;
  int tid = threadIdx.x, lane = tid & 63, w = tid >> 6;
  int rb = blockIdx.x * 128 + w * 32;

  f32x4 acc[2][8];
#pragma unroll
  for (int rf = 0; rf < 2; ++rf)
#pragma unroll
    for (int ct = 0; ct < 8; ++ct) acc[rf][ct] = (f32x4){0.f, 0.f, 0.f, 0.f};

  int r0 = rb + (lane & 15);      if (r0 > n - 1) r0 = n - 1;
  int r1 = rb + 16 + (lane & 15); if (r1 > n - 1) r1 = n - 1;
  int koff = (lane >> 4) * 8;
  const unsigned short* a0s = plane + (size_t)r0 * DIM + koff;
  const unsigned short* a1s = plane + (size_t)r1 * DIM + koff;
  const unsigned short* a0n = hn + (size_t)r0 * DIM + koff;
  const unsigned short* a1n = hn + (size_t)r1 * DIM + koff;

#define STAGE_B(kt_, buf_)                                                    \
  {                                                                           \
    const uint4* hsrc = Bhi + (size_t)(kt_) * 512;                            \
    const uint4* lsrc = Blo + (size_t)(kt_) * 512;                            \
    uint4* dstb = Bs + (size_t)(buf_) * 1024;                                 \
    dstb[tid]        = hsrc[tid];                                             \
    dstb[tid + 256]  = hsrc[tid + 256];                                       \
    dstb[tid + 512]  = lsrc[tid];                                             \
    dstb[tid + 768]  = lsrc[tid + 256];                                       \
  }

  STAGE_B(0, 0);
  __syncthreads();

#pragma unroll
  for (int kt = 0; kt < 8; ++kt) {
    if (kt < 7) STAGE_B(kt + 1, (kt + 1) & 1);
    int buf = kt & 1;
    bf16x8 a0 = (kt < 4) ? *(const bf16x8*)(a0s + kt * 32)
                         : *(const bf16x8*)(a0n + (kt - 4) * 32);
    bf16x8 a1 = (kt < 4) ? *(const bf16x8*)(a1s + kt * 32)
                         : *(const bf16x8*)(a1n + (kt - 4) * 32);
    const uint4* bb = Bs + (size_t)buf * 1024;
#pragma unroll
    for (int ct = 0; ct < 8; ++ct) {
      bf16x8 bh = *(const bf16x8*)&bb[ct * 64 + lane];
      bf16x8 bl = *(const bf16x8*)&bb[512 + ct * 64 + lane];
      acc[0][ct] = __builtin_amdgcn_mfma_f32_16x16x32_bf16(a0, bh, acc[0][ct], 0, 0, 0);
      acc[0][ct] = __builtin_amdgcn_mfma_f32_16x16x32_bf16(a0, bl, acc[0][ct], 0, 0, 0);
      acc[1][ct] = __builtin_amdgcn_mfma_f32_16x16x32_bf16(a1, bh, acc[1][ct], 0, 0, 0);
      acc[1][ct] = __builtin_amdgcn_mfma_f32_16x16x32_bf16(a1, bl, acc[1][ct], 0, 0, 0);
    }
    __syncthreads();
  }
#undef STAGE_B

  // ---- epilogue: U reused as T ----
  char* tw = U + (size_t)w * 32 * 272;
#pragma unroll
  for (int rf = 0; rf < 2; ++rf)
#pragma unroll
    for (int ct = 0; ct < 8; ++ct) {
      float bv = bias[ct * 16 + (lane & 15)];
#pragma unroll
      for (int q = 0; q < 4; ++q) {
        float val = fmaxf(acc[rf][ct][q] + bv, 0.f);
        int row = rf * 16 + (lane >> 4) * 4 + q;
        int key = ((row >> 2) & 3) << 5;
        int cb = (ct * 32 + (lane & 15) * 2) ^ key;
        *(unsigned short*)(tw + row * 272 + cb) = bf16_rne(val);
      }
    }

  if (!LAST) {
#pragma unroll
    for (int rr = 0; rr < 2; ++rr) {
      int r = rr * 16 + (lane >> 2);
      int grow = rb + r;
      if (grow < n) {
        int key = ((r >> 2) & 3) << 5;
        int cb0 = (lane & 3) * 64;
#pragma unroll
        for (int j = 0; j < 4; ++j) {
          uint4 v = *(const uint4*)(tw + r * 272 + ((cb0 + j * 16) ^ key));
          *(uint4*)(oplane + (size_t)grow * DIM + (cb0 + j * 16) / 2) = v;
        }
      }
    }
  } else {
#pragma unroll
    for (int rf = 0; rf < 2; ++rf) {
      f32x4 cacc[3];
#pragma unroll
      for (int ct = 0; ct < 3; ++ct) cacc[ct] = (f32x4){0.f, 0.f, 0.f, 0.f};
      int row = rf * 16 + (lane & 15);
      int key = ((row >> 2) & 3) << 5;
#pragma unroll
      for (int kt = 0; kt < 4; ++kt) {
        int bo = (kt * 64 + (lane >> 4) * 16) ^ key;
        bf16x8 a = *(const bf16x8*)(tw + row * 272 + bo);
#pragma unroll
        for (int ct = 0; ct < 3; ++ct) {
          bf16x8 bh = *(const bf16x8*)&Chi[(size_t)(kt * 3 + ct) * 64 + lane];
          bf16x8 bl = *(const bf16x8*)&Clo[(size_t)(kt * 3 + ct) * 64 + lane];
          cacc[ct] = __builtin_amdgcn_mfma_f32_16x16x32_bf16(a, bh, cacc[ct], 0, 0, 0);
          cacc[ct] = __builtin_amdgcn_mfma_f32_16x16x32_bf16(a, bl, cacc[ct], 0, 0, 0);
        }
      }
      int c0 = (lane & 15);
      int c1 = 16 + (lane & 15);
      int c2 = 32 + (lane & 15);
      bool v2 = c2 < NCLS;
      float b0 = bc[c0], b1 = bc[c1], b2 = v2 ? bc[c2] : 0.f;
#pragma unroll
      for (int q = 0; q < 4; ++q) {
        int grow = rb + rf * 16 + (lane >> 4) * 4 + q;
        float l0 = cacc[0][q] + b0;
        float l1 = cacc[1][q] + b1;
        float l2 = v2 ? cacc[2][q] + b2 : -FLT_MAX;
        float m = fmaxf(l0, fmaxf(l1, l2));
#pragma unroll
        for (int off = 8; off >= 1; off >>= 1) m = fmaxf(m, __shfl_xor(m, off));
        float e0 = __expf(l0 - m);
        float e1 = __expf(l1 - m);
        float e2 = v2 ? __expf(l2 - m) : 0.f;
        float sden = e0 + e1 + e2;
#pragma unroll
        for (int off = 8; off >= 1; off >>= 1) sden += __shfl_xor(sden, off);
        float inv = 1.0f / sden;
        if (grow < n) {
          out[(size_t)grow * NCLS + c0] = e0 * inv;
          out[(size_t)grow * NCLS + c1] = e1 * inv;
          if (v2) out[(size_t)grow * NCLS + c2] = e2 * inv;
        }
      }
    }
  }
}

extern "C" void kernel_launch(void* const* d_in, const int* in_sizes, int n_in,
                              void* d_out, int out_size, void* d_ws, size_t ws_size,
                              hipStream_t stream) {
  const float* feat   = (const float*)d_in[0];
  const int*   src    = (const int*)d_in[1];
  const int*   dst    = (const int*)d_in[2];
  const float* w_self = (const float*)d_in[3];
  const float* w_neigh= (const float*)d_in[4];
  const float* b      = (const float*)d_in[5];
  const float* wc     = (const float*)d_in[6];
  const float* bc     = (const float*)d_in[7];
  float* out = (float*)d_out;

  const int N = in_sizes[0] / DIM;
  const int E = in_sizes[1];
  const size_t PS  = (size_t)N * DIM;        // plane elems (data rows)
  const size_t PSP = (size_t)(N + 1) * DIM;  // +1 sentinel row

  // workspace layout (~68 MB)
  unsigned short* P0 = (unsigned short*)d_ws;   // features bf16 (+row N = 0)
  unsigned short* P1 = P0 + PSP;                // layer0 out / layer2 out
  unsigned short* P2 = P1 + PSP;                // layer1 out
  unsigned short* HN = P2 + PSP;                // neighbor means (N rows)
  int*   cnt  = (int*)(HN + PS);
  u16*   eidx = (u16*)(cnt + N);                // N*MAXD padded u16 slots
  uintptr_t aln = ((uintptr_t)(eidx + (size_t)N * MAXD) + 255) & ~(uintptr_t)255;
  uint4* Bhi = (uint4*)aln;                     // 3 * 4096
  uint4* Blo = Bhi + 3 * 4096;
  uint4* Chi = Blo + 3 * 4096;                  // 12*64
  uint4* Clo = Chi + 12 * 64;
  int* binCnt = (int*)(Clo + 12 * 64);          // 256 counters, padded x16
  unsigned* binbuf = (unsigned*)(binCnt + 4096);// 256 * BINCAP records

  // 1) zero bin counters (tiny; must precede S1 atomics)
  k_init0<<<16, 256, 0, stream>>>(binCnt);

  // 2) prep: S1 binning + packs + cvt + eidx sentinel + row-N zero
  long total8 = (long)(PS / 8);
  long t8 = (long)N * MAXD / 8;                 // ushort8 stores
  int nCvt = (int)((total8 + 255) / 256);
  int nSent = (int)((t8 + 255) / 256);
  int nS1 = (E + 4095) / 4096;
  k_prep<<<nS1 + 51 + nCvt + nSent, 256, 0, stream>>>(
      w_self, w_neigh, wc, feat, src, dst,
      Bhi, Blo, Chi, Clo, P0, P1, P2,
      binCnt, binbuf, eidx, N, total8, t8, E, nS1, nCvt);

  // 3) S2: per-bin CSR build (LDS ranks, no global atomics)
  int nbins = (N + 255) >> 8;
  k_csr<<<nbins, 256, 0, stream>>>(binbuf, binCnt, cnt, eidx, N);

  // 4-9) layers (classifier fused into last mm)
  const unsigned short* hin = P0;
  unsigned short* houts[2] = {P1, P2};
  for (int l = 0; l < 3; ++l) {
    k_agg9<<<(N + 3) / 4, 256, 0, stream>>>(hin, HN, cnt, eidx, N);
    if (l < 2) {
      k_mm2<0><<<(N + 127) / 128, 256, 0, stream>>>(hin, HN,
          Bhi + (size_t)l * 4096, Blo + (size_t)l * 4096,
          b + (size_t)l * DIM, houts[l], Chi, Clo, bc, out, N);
      hin = houts[l];
    } else {
      k_mm2<1><<<(N + 127) / 128, 256, 0, stream>>>(hin, HN,
          Bhi + (size_t)l * 4096, Blo + (size_t)l * 4096,
          b + (size_t)l * DIM, (unsigned short*)nullptr, Chi, Clo, bc, out, N);
    }
  }
}